// Round 2
// baseline (1460.815 us; speedup 1.0000x reference)
//
#include <hip/hip_runtime.h>
#include <hip/hip_bf16.h>

// Problem constants
#define BB 4096
#define NNA 11
#define BN (BB*NNA)      // 45056

// ws float offsets (f32 scratch)
#define OFF_WEFF   0         // [4][256]
#define OFF_BIASL  1024      // [12][256]
#define OFF_WBIG   4096      // [48][256]
#define OFF_BIAS2  16384     // [256]
#define OFF_WALL   16640     // [48][256]
#define OFF_BIASN  28928     // [11][256]
#define OFF_WG1F   31744     // [48][1152]
#define OFF_BIASG1 87040     // [11][1152]
#define OFF_WG2    99712     // [1536][128] (rows 1520..1535 zero)
#define OFF_MIX    296320    // [4096][242]  attn(121)|A(121)
#define OFF_INTER  1287552   // bf16 region start (float-offset): inter[BN][256], hyp[BN][256]

__device__ __forceinline__ float b2f(__hip_bfloat16 x) { return __bfloat162float(x); }

// ---------- Prologue: weight folding (all f32) ----------

// grid 13: blk0 -> W_eff = W_in @ W_pos[0:256]; blk 1..12 -> biasL[l] = b_pos + b_in@Wp_top + pe[l]@Wp_bot
__global__ __launch_bounds__(256) void k_p1(const float* W_in, const float* b_in,
                                            const float* W_pos, const float* b_pos,
                                            float* ws) {
  int d = threadIdx.x, blk = blockIdx.x;
  if (blk == 0) {
    for (int c = 0; c < 4; ++c) {
      float s = 0.f;
      for (int j = 0; j < 256; ++j)
        s += W_in[c*256+j] * W_pos[j*256+d];
      ws[OFF_WEFF + c*256 + d] = s;
    }
  } else {
    int l = blk - 1;
    float s = b_pos[d];
    for (int j = 0; j < 256; ++j)
      s += b_in[j] * W_pos[j*256+d];
    float coef = -logf(10000.f) / 256.f;
    for (int i = 0; i < 128; ++i) {
      float div = expf(coef * (float)(2*i));
      float ang = (float)l * div;
      s += sinf(ang) * W_pos[(256+2*i)*256+d];
      s += cosf(ang) * W_pos[(256+2*i+1)*256+d];
    }
    ws[OFF_BIASL + l*256 + d] = s;
  }
}

// grid 49: blk<48 -> W_big[lc] = W_eff[c] @ W_fc2_l ; blk48 -> bias2 = b_fc2 + sum_l biasL[l]@W_fc2_l
__global__ __launch_bounds__(256) void k_p2(const float* W_fc2, const float* b_fc2,
                                            float* ws) {
  int d = threadIdx.x, blk = blockIdx.x;
  if (blk < 48) {
    int l = blk >> 2, c = blk & 3;
    float s = 0.f;
    for (int j = 0; j < 256; ++j)
      s += ws[OFF_WEFF + c*256 + j] * W_fc2[(l*256+j)*256 + d];
    ws[OFF_WBIG + blk*256 + d] = s;
  } else {
    float s = b_fc2[d];
    for (int l = 0; l < 12; ++l)
      for (int j = 0; j < 256; ++j)
        s += ws[OFF_BIASL + l*256 + j] * W_fc2[(l*256+j)*256 + d];
    ws[OFF_BIAS2 + d] = s;
  }
}

// grid 59: blk<48 -> W_all = W_big @ W_fc3_top ; blk 48..58 -> bias_n
__global__ __launch_bounds__(256) void k_p3(const float* W_fc3, const float* b_fc3,
                                            float* ws) {
  int d = threadIdx.x, blk = blockIdx.x;
  if (blk < 48) {
    float s = 0.f;
    for (int j = 0; j < 256; ++j)
      s += ws[OFF_WBIG + blk*256 + j] * W_fc3[j*256 + d];
    ws[OFF_WALL + blk*256 + d] = s;
  } else {
    int n = blk - 48;
    float s = b_fc3[d] + W_fc3[(256+n)*256 + d];
    for (int j = 0; j < 256; ++j)
      s += ws[OFF_BIAS2 + j] * W_fc3[j*256 + d];
    ws[OFF_BIASN + n*256 + d] = s;
  }
}

// Wg1 column map: [Wm_top|Wm_bot|Wh_top|Wh_bot|Wo_ftraj] (1152 cols)
__device__ __forceinline__ float wg1_elem(int j, int col, const float* W_msg,
                                          const float* W_hyp, const float* W_out) {
  if (col < 256)       return W_msg[j*256 + col];
  else if (col < 512)  return W_msg[(256+j)*256 + (col-256)];
  else if (col < 768)  return W_hyp[j*256 + (col-512)];
  else if (col < 1024) return W_hyp[(256+j)*256 + (col-768)];
  else                 return W_out[(960+j)*128 + (col-1024)];
}

// grid 59: blk<48 -> Wg1f[k] = W_all[k] @ Wg1 ; blk 48..58 -> biasg1[n] = bias_n[n]@Wg1 + [b_msg|0|b_hyp|0|0]
__global__ __launch_bounds__(256) void k_p4(const float* W_msg, const float* b_msg,
                                            const float* W_hyp, const float* b_hyp,
                                            const float* W_out, float* ws) {
  __shared__ float row[256];
  int t = threadIdx.x, blk = blockIdx.x;
  bool isb = blk >= 48;
  int idx = isb ? (blk - 48) : blk;
  row[t] = isb ? ws[OFF_BIASN + idx*256 + t] : ws[OFF_WALL + idx*256 + t];
  __syncthreads();
  for (int col = t; col < 1152; col += 256) {
    float s = 0.f;
    for (int j = 0; j < 256; ++j)
      s += row[j] * wg1_elem(j, col, W_msg, W_hyp, W_out);
    if (isb) {
      if (col < 256) s += b_msg[col];
      else if (col >= 512 && col < 768) s += b_hyp[col-512];
      ws[OFF_BIASG1 + idx*1152 + col] = s;
    } else {
      ws[OFF_WG1F + idx*1152 + col] = s;
    }
  }
}

// grid 1536, block 128: pack Wg2[1536][128]:
// rows 0..959: W_out past; 960..1215: W_out inter-rows; 1216..1471: W_line@W_out_feat; 1472..1519: Wg1f[:,1024:]; rest 0
__global__ __launch_bounds__(128) void k_p5(const float* W_line, const float* W_out,
                                            float* ws) {
  int c = threadIdx.x, r = blockIdx.x;
  float v;
  if (r < 960)       v = W_out[r*128 + c];
  else if (r < 1216) v = W_out[(r+256)*128 + c];
  else if (r < 1472) {
    int dd = r - 1216;
    float s = 0.f;
    for (int j = 0; j < 64; ++j)
      s += W_line[dd*64 + j] * W_out[(1472+j)*128 + c];
    v = s;
  } else if (r < 1520) {
    v = ws[OFF_WG1F + (r-1472)*1152 + 1024 + c];
  } else v = 0.f;
  ws[OFF_WG2 + r*128 + c] = v;
}

// ---------- Front: ftraj GEMM (K=48) + per-scene corr -> attn/A ----------
// grid 1024: 4 scenes (44 rows) per block; one wave per scene for corr/attn/A.
__global__ __launch_bounds__(256) void k_front(const float* inputs, float* ws) {
  __shared__ float XT[48*44];     // transposed x: XT[k*44 + r]
  __shared__ float F[44*260];     // ftraj tile, padded stride 260 (16B aligned rows)
  __shared__ float C[4*121];      // per-scene gram
  int t = threadIdx.x;
  int R0 = blockIdx.x * 44;
  for (int i = t; i < 44*48; i += 256) {
    int r = i / 48, k = i - r*48;
    XT[k*44 + r] = inputs[(size_t)(R0+r)*48 + k];
  }
  __syncthreads();
  { // ftraj = X48 @ W_all + bias_n ; thread = output col d
    int d = t;
    float acc[44];
    #pragma unroll
    for (int r = 0; r < 44; ++r) acc[r] = ws[OFF_BIASN + (r % 11)*256 + d];
    for (int k = 0; k < 48; ++k) {
      float w = ws[OFF_WALL + k*256 + d];
      #pragma unroll
      for (int j = 0; j < 11; ++j) {
        float4 xv = *(const float4*)&XT[k*44 + 4*j];
        acc[4*j+0] += xv.x*w; acc[4*j+1] += xv.y*w;
        acc[4*j+2] += xv.z*w; acc[4*j+3] += xv.w*w;
      }
    }
    #pragma unroll
    for (int r = 0; r < 44; ++r) F[r*260 + d] = acc[r];
  }
  __syncthreads();
  int w = t >> 6, lane = t & 63;
  { // gram: 66 unique pairs per scene, one wave per scene
    const float4* F4 = (const float4*)F;   // row stride 65 float4s
    for (int p = lane; p < 66; p += 64) {
      int n = 0, pp = p;
      while (pp >= 11 - n) { pp -= 11 - n; ++n; }
      int m = n + pp;
      int ra = (w*11 + n) * 65, rb2 = (w*11 + m) * 65;
      float s = 0.f;
      #pragma unroll 4
      for (int j = 0; j < 64; ++j) {
        float4 a = F4[ra + j], b = F4[rb2 + j];
        s += a.x*b.x + a.y*b.y + a.z*b.z + a.w*b.w;
      }
      C[w*121 + n*11 + m] = s;
      C[w*121 + m*11 + n] = s;
    }
  }
  __syncthreads();
  { // attn (softmax of C/16) and A (thresholded, degree-normalized)
    float* Cw = C + w*121;
    float rn[11];
    #pragma unroll
    for (int n = 0; n < 11; ++n) rn[n] = 1.f / sqrtf(Cw[n*11+n]);
    float a = 1e30f;
    for (int n = 0; n < 11; ++n)
      for (int m = 0; m < 11; ++m)
        a = fminf(a, Cw[n*11+m] * rn[n] * rn[m]);
    float thr = (a < 0.4f) ? 0.4f : (((a > 0.4f) && (a < 0.6f)) ? a + 0.1f : a + 0.03f);
    int scene = blockIdx.x*4 + w;
    float* mixb = ws + OFF_MIX + (size_t)scene*242;
    if (lane < 11) {
      int n = lane;
      float mx = -1e30f;
      #pragma unroll
      for (int m = 0; m < 11; ++m) mx = fmaxf(mx, Cw[n*11+m]);
      mx *= (1.f/16.f);
      float e[11], ssum = 0.f;
      #pragma unroll
      for (int m = 0; m < 11; ++m) { e[m] = expf(Cw[n*11+m]*(1.f/16.f) - mx); ssum += e[m]; }
      float inv = 1.f / ssum;
      #pragma unroll
      for (int m = 0; m < 11; ++m) mixb[n*11+m] = e[m]*inv;
      float keep[11], cnt = 0.f;
      #pragma unroll
      for (int m = 0; m < 11; ++m) {
        float q = Cw[n*11+m] * rn[n] * rn[m];
        keep[m] = (q >= thr) ? 1.f : 0.f; cnt += keep[m];
      }
      float sc = 1.f / fmaxf(cnt, 1.f);
      #pragma unroll
      for (int m = 0; m < 11; ++m) mixb[121 + n*11 + m] = keep[m]*sc;
    }
  }
}

// ---------- Mix: P = X48 @ Wg1f (+bias), register attn/A mixing, relu -> inter/hyp (bf16) ----------
// grid (2048, 2): 2 scenes (22 rows) per block; gy=0 -> msg/inter (attn), gy=1 -> hyp (A).
__global__ __launch_bounds__(256) void k_mix(const float* inputs, float* ws,
                                             __hip_bfloat16* outI, __hip_bfloat16* outH) {
  __shared__ float XT[48*24];   // XT[k*24+r], rows 22,23 zero
  __shared__ float MW[2*121];
  int t = threadIdx.x;
  int s0 = blockIdx.x * 2;
  int R0 = s0 * 11;
  int gy = blockIdx.y;
  __hip_bfloat16* dst = gy ? outH : outI;
  for (int i = t; i < 22*48; i += 256) {
    int r = i / 48, k = i - r*48;
    XT[k*24 + r] = inputs[(size_t)(R0+r)*48 + k];
  }
  for (int i = t; i < 96; i += 256) { int k = i >> 1, r = 22 + (i & 1); XT[k*24+r] = 0.f; }
  for (int i = t; i < 242; i += 256) {
    int s = i / 121, j = i - s*121;
    MW[i] = ws[OFF_MIX + (size_t)(s0+s)*242 + gy*121 + j];
  }
  __syncthreads();
  int gc = gy*512 + t;           // top col; bot col = gc+256
  float accT[24], accB[24];
  #pragma unroll
  for (int r = 0; r < 24; ++r) {
    if (r < 22) {
      accT[r] = ws[OFF_BIASG1 + (r % 11)*1152 + gc];
      accB[r] = ws[OFF_BIASG1 + (r % 11)*1152 + gc + 256];
    } else { accT[r] = 0.f; accB[r] = 0.f; }
  }
  for (int k = 0; k < 48; ++k) {
    float wt = ws[OFF_WG1F + k*1152 + gc];
    float wb = ws[OFF_WG1F + k*1152 + gc + 256];
    #pragma unroll
    for (int j = 0; j < 6; ++j) {
      float4 xv = *(const float4*)&XT[k*24 + 4*j];
      accT[4*j+0] += xv.x*wt; accT[4*j+1] += xv.y*wt; accT[4*j+2] += xv.z*wt; accT[4*j+3] += xv.w*wt;
      accB[4*j+0] += xv.x*wb; accB[4*j+1] += xv.y*wb; accB[4*j+2] += xv.z*wb; accB[4*j+3] += xv.w*wb;
    }
  }
  #pragma unroll
  for (int s = 0; s < 2; ++s)
    #pragma unroll
    for (int n = 0; n < 11; ++n) {
      float v = accT[s*11+n];
      #pragma unroll
      for (int m = 0; m < 11; ++m)
        v += MW[s*121 + n*11 + m] * accB[s*11+m];
      v = fmaxf(v, 0.f);
      dst[(size_t)(R0 + s*11 + n)*256 + t] = __float2bfloat16(v);
    }
}

// ---------- Tail GEMM: h = relu([past|inter|hyp|X48] @ Wg2 + biases), out = h @ W_qz + b_qz ----------
// grid 704: 64 rows/block. 4x8 register tile per thread; K staged in LDS chunks of 64.
__global__ __launch_bounds__(256) void k_g2(const float* past, const float* inputs,
                                            const float* b_out, const float* W_qz,
                                            const float* b_qz,
                                            const __hip_bfloat16* interI, const __hip_bfloat16* hypI,
                                            float* ws, float* out) {
  __shared__ float lds[16448];   // [0..4352) xT(64k x 68) | [4352..12544) wch(64x128) ; later hs(64x129)@0, WQ@8256
  const int XT_OFF = 0, WCH_OFF = 4352, HS_OFF = 0, WQ_OFF = 8256;
  int t = threadIdx.x;
  int R0 = blockIdx.x * 64;
  int tc = t & 15, tr = t >> 4;     // cols 8tc..8tc+7, rows 4tr..4tr+3
  float acc[32];
  #pragma unroll
  for (int jj = 0; jj < 4; ++jj) {
    int row = 4*tr + jj;
    int n = (R0 + row) % 11;
    #pragma unroll
    for (int cc = 0; cc < 8; ++cc) {
      int c = 8*tc + cc;
      acc[jj*8+cc] = b_out[c] + ws[OFF_BIASG1 + n*1152 + 1024 + c];
    }
  }
  for (int ch = 0; ch < 24; ++ch) {
    const void* src; int stride, koff, kw, isb;
    if (ch < 15)      { src = past;   stride = 960; koff = ch*64;      kw = 64; isb = 0; }
    else if (ch < 19) { src = interI; stride = 256; koff = (ch-15)*64; kw = 64; isb = 1; }
    else if (ch < 23) { src = hypI;   stride = 256; koff = (ch-19)*64; kw = 64; isb = 1; }
    else              { src = inputs; stride = 48;  koff = 0;          kw = 48; isb = 0; }
    int k0 = ch*64;
    __syncthreads();
    for (int i = t; i < 4096; i += 256) {       // xT stage (transposed, pad-68)
      int r = i >> 6, k = i & 63;
      float v = 0.f;
      if (k < kw) {
        size_t idx = (size_t)(R0+r)*stride + koff + k;
        v = isb ? b2f(((const __hip_bfloat16*)src)[idx]) : ((const float*)src)[idx];
      }
      lds[XT_OFF + k*68 + r] = v;
    }
    for (int i = t; i < 8192; i += 256) {       // w chunk stage
      int k = i >> 7, c = i & 127;
      lds[WCH_OFF + k*128 + c] = ws[OFF_WG2 + (size_t)(k0+k)*128 + c];
    }
    __syncthreads();
    #pragma unroll 4
    for (int k = 0; k < 64; ++k) {
      float4 xv  = *(const float4*)&lds[XT_OFF + k*68 + 4*tr];
      float4 wlo = *(const float4*)&lds[WCH_OFF + k*128 + 8*tc];
      float4 whi = *(const float4*)&lds[WCH_OFF + k*128 + 8*tc + 4];
      float xa[4] = {xv.x, xv.y, xv.z, xv.w};
      float wa[8] = {wlo.x, wlo.y, wlo.z, wlo.w, whi.x, whi.y, whi.z, whi.w};
      #pragma unroll
      for (int jj = 0; jj < 4; ++jj)
        #pragma unroll
        for (int cc = 0; cc < 8; ++cc)
          acc[jj*8+cc] += xa[jj]*wa[cc];
    }
  }
  __syncthreads();
  #pragma unroll
  for (int jj = 0; jj < 4; ++jj)
    #pragma unroll
    for (int cc = 0; cc < 8; ++cc)
      lds[HS_OFF + (4*tr+jj)*129 + 8*tc + cc] = fmaxf(acc[jj*8+cc], 0.f);
  for (int i = t; i < 8192; i += 256) lds[WQ_OFF + i] = W_qz[i];
  __syncthreads();
  { // qz epilogue: out = h @ W_qz + b_qz
    int r = t >> 2, zq = t & 3;
    float a2[16];
    #pragma unroll
    for (int j = 0; j < 16; ++j) a2[j] = b_qz[zq*16 + j];
    for (int cc = 0; cc < 128; ++cc) {
      float hv = lds[HS_OFF + r*129 + cc];
      #pragma unroll
      for (int j4 = 0; j4 < 4; ++j4) {
        float4 wv = *(const float4*)&lds[WQ_OFF + cc*64 + zq*16 + j4*4];
        a2[j4*4+0] += hv*wv.x; a2[j4*4+1] += hv*wv.y;
        a2[j4*4+2] += hv*wv.z; a2[j4*4+3] += hv*wv.w;
      }
    }
    #pragma unroll
    for (int j = 0; j < 16; ++j)
      out[(size_t)(R0+r)*64 + zq*16 + j] = a2[j];
  }
}

extern "C" void kernel_launch(void* const* d_in, const int* in_sizes, int n_in,
                              void* d_out, int out_size, void* d_ws, size_t ws_size,
                              hipStream_t stream) {
  const float* inputs = (const float*)d_in[0];
  const float* past   = (const float*)d_in[1];
  const float* W_in   = (const float*)d_in[2];
  const float* b_in   = (const float*)d_in[3];
  const float* W_pos  = (const float*)d_in[4];
  const float* b_pos  = (const float*)d_in[5];
  const float* W_fc2  = (const float*)d_in[6];
  const float* b_fc2  = (const float*)d_in[7];
  const float* W_fc3  = (const float*)d_in[8];
  const float* b_fc3  = (const float*)d_in[9];
  const float* W_msg  = (const float*)d_in[10];
  const float* b_msg  = (const float*)d_in[11];
  const float* W_hyp  = (const float*)d_in[12];
  const float* b_hyp  = (const float*)d_in[13];
  const float* W_line = (const float*)d_in[14];
  const float* W_out  = (const float*)d_in[15];
  const float* b_out  = (const float*)d_in[16];
  const float* W_qz   = (const float*)d_in[17];
  const float* b_qz   = (const float*)d_in[18];
  float* ws = (float*)d_ws;
  __hip_bfloat16* interI = (__hip_bfloat16*)(ws + OFF_INTER);
  __hip_bfloat16* hypI   = interI + (size_t)BN*256;
  float* outp   = (float*)d_out;

  hipLaunchKernelGGL(k_p1, dim3(13),  dim3(256), 0, stream, W_in, b_in, W_pos, b_pos, ws);
  hipLaunchKernelGGL(k_p2, dim3(49),  dim3(256), 0, stream, W_fc2, b_fc2, ws);
  hipLaunchKernelGGL(k_p3, dim3(59),  dim3(256), 0, stream, W_fc3, b_fc3, ws);
  hipLaunchKernelGGL(k_p4, dim3(59),  dim3(256), 0, stream, W_msg, b_msg, W_hyp, b_hyp, W_out, ws);
  hipLaunchKernelGGL(k_p5, dim3(1536), dim3(128), 0, stream, W_line, W_out, ws);
  hipLaunchKernelGGL(k_front, dim3(1024), dim3(256), 0, stream, inputs, ws);
  hipLaunchKernelGGL(k_mix, dim3(2048, 2), dim3(256), 0, stream, inputs, ws, interI, hypI);
  hipLaunchKernelGGL(k_g2, dim3(704), dim3(256), 0, stream, past, inputs, b_out, W_qz, b_qz,
                     interI, hypI, ws, outp);
}

// Round 3
// 963.768 us; speedup vs baseline: 1.5157x; 1.5157x over previous
//
#include <hip/hip_runtime.h>
#include <hip/hip_bf16.h>

// Problem constants
#define BB 4096
#define NNA 11
#define BN (BB*NNA)      // 45056

// ws float offsets (f32 scratch unless noted)
#define OFF_WEFF   0         // [4][256]
#define OFF_BIASL  1024      // [12][256]
#define OFF_WBIG   4096      // [48][256]
#define OFF_BIAS2  16384     // [256]
#define OFF_WALL   16640     // [48][256]
#define OFF_BIASN  28928     // [11][256]
#define OFF_WG1F   31744     // [48][1152]
#define OFF_BIASG1 87040     // [11][1152]
#define OFF_WG2    99712     // bf16 WT[128][1536] (transposed tail weight), 98304 floats
#define OFF_WQT    198656    // bf16 WQT[64][128], 4096 floats
#define OFF_MIX    296320    // [4096][242]  attn(121)|A(121)
#define OFF_INTER  1287552   // bf16 region start (float-offset): inter[BN][256], hyp[BN][256]

typedef short bh8 __attribute__((ext_vector_type(8)));   // 8 bf16 (4 VGPRs) MFMA A/B frag
typedef float fx4 __attribute__((ext_vector_type(4)));   // MFMA C/D frag

__device__ __forceinline__ float b2f(__hip_bfloat16 x) { return __bfloat162float(x); }
__device__ __forceinline__ short f2bs(float v) { __hip_bfloat16 h = __float2bfloat16(v); return *(short*)&h; }

// ---------- Prologue: weight folding (all f32) ----------

// grid 13: blk0 -> W_eff = W_in @ W_pos[0:256]; blk 1..12 -> biasL[l] = b_pos + b_in@Wp_top + pe[l]@Wp_bot
__global__ __launch_bounds__(256) void k_p1(const float* W_in, const float* b_in,
                                            const float* W_pos, const float* b_pos,
                                            float* ws) {
  int d = threadIdx.x, blk = blockIdx.x;
  if (blk == 0) {
    for (int c = 0; c < 4; ++c) {
      float s = 0.f;
      for (int j = 0; j < 256; ++j)
        s += W_in[c*256+j] * W_pos[j*256+d];
      ws[OFF_WEFF + c*256 + d] = s;
    }
  } else {
    int l = blk - 1;
    float s = b_pos[d];
    for (int j = 0; j < 256; ++j)
      s += b_in[j] * W_pos[j*256+d];
    float coef = -logf(10000.f) / 256.f;
    for (int i = 0; i < 128; ++i) {
      float div = expf(coef * (float)(2*i));
      float ang = (float)l * div;
      s += sinf(ang) * W_pos[(256+2*i)*256+d];
      s += cosf(ang) * W_pos[(256+2*i+1)*256+d];
    }
    ws[OFF_BIASL + l*256 + d] = s;
  }
}

// grid 49: blk<48 -> W_big[lc] = W_eff[c] @ W_fc2_l ; blk48 -> bias2 = b_fc2 + sum_l biasL[l]@W_fc2_l
__global__ __launch_bounds__(256) void k_p2(const float* W_fc2, const float* b_fc2,
                                            float* ws) {
  int d = threadIdx.x, blk = blockIdx.x;
  if (blk < 48) {
    int l = blk >> 2, c = blk & 3;
    float s = 0.f;
    for (int j = 0; j < 256; ++j)
      s += ws[OFF_WEFF + c*256 + j] * W_fc2[(l*256+j)*256 + d];
    ws[OFF_WBIG + blk*256 + d] = s;
  } else {
    float s = b_fc2[d];
    for (int l = 0; l < 12; ++l)
      for (int j = 0; j < 256; ++j)
        s += ws[OFF_BIASL + l*256 + j] * W_fc2[(l*256+j)*256 + d];
    ws[OFF_BIAS2 + d] = s;
  }
}

// grid 59: blk<48 -> W_all = W_big @ W_fc3_top ; blk 48..58 -> bias_n
__global__ __launch_bounds__(256) void k_p3(const float* W_fc3, const float* b_fc3,
                                            float* ws) {
  int d = threadIdx.x, blk = blockIdx.x;
  if (blk < 48) {
    float s = 0.f;
    for (int j = 0; j < 256; ++j)
      s += ws[OFF_WBIG + blk*256 + j] * W_fc3[j*256 + d];
    ws[OFF_WALL + blk*256 + d] = s;
  } else {
    int n = blk - 48;
    float s = b_fc3[d] + W_fc3[(256+n)*256 + d];
    for (int j = 0; j < 256; ++j)
      s += ws[OFF_BIAS2 + j] * W_fc3[j*256 + d];
    ws[OFF_BIASN + n*256 + d] = s;
  }
}

// Wg1 column map: [Wm_top|Wm_bot|Wh_top|Wh_bot|Wo_ftraj] (1152 cols)
__device__ __forceinline__ float wg1_elem(int j, int col, const float* W_msg,
                                          const float* W_hyp, const float* W_out) {
  if (col < 256)       return W_msg[j*256 + col];
  else if (col < 512)  return W_msg[(256+j)*256 + (col-256)];
  else if (col < 768)  return W_hyp[j*256 + (col-512)];
  else if (col < 1024) return W_hyp[(256+j)*256 + (col-768)];
  else                 return W_out[(960+j)*128 + (col-1024)];
}

// grid 59: blk<48 -> Wg1f[k] = W_all[k] @ Wg1 ; blk 48..58 -> biasg1[n] = bias_n[n]@Wg1 + [b_msg|0|b_hyp|0|0]
__global__ __launch_bounds__(256) void k_p4(const float* W_msg, const float* b_msg,
                                            const float* W_hyp, const float* b_hyp,
                                            const float* W_out, float* ws) {
  __shared__ float row[256];
  int t = threadIdx.x, blk = blockIdx.x;
  bool isb = blk >= 48;
  int idx = isb ? (blk - 48) : blk;
  row[t] = isb ? ws[OFF_BIASN + idx*256 + t] : ws[OFF_WALL + idx*256 + t];
  __syncthreads();
  for (int col = t; col < 1152; col += 256) {
    float s = 0.f;
    for (int j = 0; j < 256; ++j)
      s += row[j] * wg1_elem(j, col, W_msg, W_hyp, W_out);
    if (isb) {
      if (col < 256) s += b_msg[col];
      else if (col >= 512 && col < 768) s += b_hyp[col-512];
      ws[OFF_BIASG1 + idx*1152 + col] = s;
    } else {
      ws[OFF_WG1F + idx*1152 + col] = s;
    }
  }
}

// grid 1536, block 128: WT[c][r] (bf16, transposed) for the tail MFMA GEMM:
// rows 0..959: W_out past; 960..1215: W_out inter-rows; 1216..1471: W_line@W_out_feat; 1472..1519: Wg1f[:,1024:]; rest 0
__global__ __launch_bounds__(128) void k_p5(const float* W_line, const float* W_out,
                                            float* ws) {
  int c = threadIdx.x, r = blockIdx.x;
  float v;
  if (r < 960)       v = W_out[r*128 + c];
  else if (r < 1216) v = W_out[(r+256)*128 + c];
  else if (r < 1472) {
    int dd = r - 1216;
    float s = 0.f;
    for (int j = 0; j < 64; ++j)
      s += W_line[dd*64 + j] * W_out[(1472+j)*128 + c];
    v = s;
  } else if (r < 1520) {
    v = ws[OFF_WG1F + (r-1472)*1152 + 1024 + c];
  } else v = 0.f;
  short* WTs = (short*)(ws + OFF_WG2);
  WTs[(size_t)c*1536 + r] = f2bs(v);
}

// grid 32, block 256: WQT[n][k] = bf16(W_qz[k][n]) for the qz epilogue MFMA
__global__ __launch_bounds__(256) void k_p6(const float* W_qz, float* ws) {
  int i = blockIdx.x*256 + threadIdx.x;
  int n = i >> 7, k = i & 127;
  short* WQs = (short*)(ws + OFF_WQT);
  WQs[n*128 + k] = f2bs(W_qz[k*64 + n]);
}

// ---------- Front: ftraj GEMM (K=48) + per-scene corr -> attn/A ----------
// grid 1024: 4 scenes (44 rows) per block; one wave per scene for corr/attn/A.
__global__ __launch_bounds__(256) void k_front(const float* inputs, float* ws) {
  __shared__ float XT[48*44];     // transposed x: XT[k*44 + r]
  __shared__ float F[44*260];     // ftraj tile, padded stride 260 (16B aligned rows)
  __shared__ float C[4*121];      // per-scene gram
  int t = threadIdx.x;
  int R0 = blockIdx.x * 44;
  for (int i = t; i < 44*48; i += 256) {
    int r = i / 48, k = i - r*48;
    XT[k*44 + r] = inputs[(size_t)(R0+r)*48 + k];
  }
  __syncthreads();
  { // ftraj = X48 @ W_all + bias_n ; thread = output col d
    int d = t;
    float acc[44];
    #pragma unroll
    for (int r = 0; r < 44; ++r) acc[r] = ws[OFF_BIASN + (r % 11)*256 + d];
    for (int k = 0; k < 48; ++k) {
      float w = ws[OFF_WALL + k*256 + d];
      #pragma unroll
      for (int j = 0; j < 11; ++j) {
        float4 xv = *(const float4*)&XT[k*44 + 4*j];
        acc[4*j+0] += xv.x*w; acc[4*j+1] += xv.y*w;
        acc[4*j+2] += xv.z*w; acc[4*j+3] += xv.w*w;
      }
    }
    #pragma unroll
    for (int r = 0; r < 44; ++r) F[r*260 + d] = acc[r];
  }
  __syncthreads();
  int w = t >> 6, lane = t & 63;
  { // gram: 66 unique pairs per scene, one wave per scene
    const float4* F4 = (const float4*)F;   // row stride 65 float4s
    for (int p = lane; p < 66; p += 64) {
      int n = 0, pp = p;
      while (pp >= 11 - n) { pp -= 11 - n; ++n; }
      int m = n + pp;
      int ra = (w*11 + n) * 65, rb2 = (w*11 + m) * 65;
      float s = 0.f;
      #pragma unroll 4
      for (int j = 0; j < 64; ++j) {
        float4 a = F4[ra + j], b = F4[rb2 + j];
        s += a.x*b.x + a.y*b.y + a.z*b.z + a.w*b.w;
      }
      C[w*121 + n*11 + m] = s;
      C[w*121 + m*11 + n] = s;
    }
  }
  __syncthreads();
  { // attn (softmax of C/16) and A (thresholded, degree-normalized)
    float* Cw = C + w*121;
    float rn[11];
    #pragma unroll
    for (int n = 0; n < 11; ++n) rn[n] = 1.f / sqrtf(Cw[n*11+n]);
    float a = 1e30f;
    for (int n = 0; n < 11; ++n)
      for (int m = 0; m < 11; ++m)
        a = fminf(a, Cw[n*11+m] * rn[n] * rn[m]);
    float thr = (a < 0.4f) ? 0.4f : (((a > 0.4f) && (a < 0.6f)) ? a + 0.1f : a + 0.03f);
    int scene = blockIdx.x*4 + w;
    float* mixb = ws + OFF_MIX + (size_t)scene*242;
    if (lane < 11) {
      int n = lane;
      float mx = -1e30f;
      #pragma unroll
      for (int m = 0; m < 11; ++m) mx = fmaxf(mx, Cw[n*11+m]);
      mx *= (1.f/16.f);
      float e[11], ssum = 0.f;
      #pragma unroll
      for (int m = 0; m < 11; ++m) { e[m] = expf(Cw[n*11+m]*(1.f/16.f) - mx); ssum += e[m]; }
      float inv = 1.f / ssum;
      #pragma unroll
      for (int m = 0; m < 11; ++m) mixb[n*11+m] = e[m]*inv;
      float keep[11], cnt = 0.f;
      #pragma unroll
      for (int m = 0; m < 11; ++m) {
        float q = Cw[n*11+m] * rn[n] * rn[m];
        keep[m] = (q >= thr) ? 1.f : 0.f; cnt += keep[m];
      }
      float sc = 1.f / fmaxf(cnt, 1.f);
      #pragma unroll
      for (int m = 0; m < 11; ++m) mixb[121 + n*11 + m] = keep[m]*sc;
    }
  }
}

// ---------- Mix: P = X48 @ Wg1f (+bias), register attn/A mixing, relu -> inter/hyp (bf16) ----------
// grid (2048, 2): 2 scenes (22 rows) per block; gy=0 -> msg/inter (attn), gy=1 -> hyp (A).
__global__ __launch_bounds__(256) void k_mix(const float* inputs, float* ws,
                                             __hip_bfloat16* outI, __hip_bfloat16* outH) {
  __shared__ float XT[48*24];   // XT[k*24+r], rows 22,23 zero
  __shared__ float MW[2*121];
  int t = threadIdx.x;
  int s0 = blockIdx.x * 2;
  int R0 = s0 * 11;
  int gy = blockIdx.y;
  __hip_bfloat16* dst = gy ? outH : outI;
  for (int i = t; i < 22*48; i += 256) {
    int r = i / 48, k = i - r*48;
    XT[k*24 + r] = inputs[(size_t)(R0+r)*48 + k];
  }
  for (int i = t; i < 96; i += 256) { int k = i >> 1, r = 22 + (i & 1); XT[k*24+r] = 0.f; }
  for (int i = t; i < 242; i += 256) {
    int s = i / 121, j = i - s*121;
    MW[i] = ws[OFF_MIX + (size_t)(s0+s)*242 + gy*121 + j];
  }
  __syncthreads();
  int gc = gy*512 + t;           // top col; bot col = gc+256
  float accT[24], accB[24];
  #pragma unroll
  for (int r = 0; r < 24; ++r) {
    if (r < 22) {
      accT[r] = ws[OFF_BIASG1 + (r % 11)*1152 + gc];
      accB[r] = ws[OFF_BIASG1 + (r % 11)*1152 + gc + 256];
    } else { accT[r] = 0.f; accB[r] = 0.f; }
  }
  for (int k = 0; k < 48; ++k) {
    float wt = ws[OFF_WG1F + k*1152 + gc];
    float wb = ws[OFF_WG1F + k*1152 + gc + 256];
    #pragma unroll
    for (int j = 0; j < 6; ++j) {
      float4 xv = *(const float4*)&XT[k*24 + 4*j];
      accT[4*j+0] += xv.x*wt; accT[4*j+1] += xv.y*wt; accT[4*j+2] += xv.z*wt; accT[4*j+3] += xv.w*wt;
      accB[4*j+0] += xv.x*wb; accB[4*j+1] += xv.y*wb; accB[4*j+2] += xv.z*wb; accB[4*j+3] += xv.w*wb;
    }
  }
  #pragma unroll
  for (int s = 0; s < 2; ++s)
    #pragma unroll
    for (int n = 0; n < 11; ++n) {
      float v = accT[s*11+n];
      #pragma unroll
      for (int m = 0; m < 11; ++m)
        v += MW[s*121 + n*11 + m] * accB[s*11+m];
      v = fmaxf(v, 0.f);
      dst[(size_t)(R0 + s*11 + n)*256 + t] = __float2bfloat16(v);
    }
}

// ---------- Tail: bf16 MFMA GEMM. h = relu([past|inter|hyp|X48] @ WT^T + biases); out = h @ WQT^T + b_qz ----------
// grid 704, block 256 (4 waves). Tile M=64 x N=128, K=1536 in 24 chunks of 64.
// LDS (shorts): A[64][72] @0 (4608) | BT[128][72] @4608 (9216) ; epilogue: hs[64][136] @0 | WQ[64][136] @8704.
#define A_OFF 0
#define BT_OFF 4608
#define HS_OFF 0
#define WQ_OFF 8704
__global__ __launch_bounds__(256) void k_g2(const float* past, const float* inputs,
                                            const float* b_out, const float* b_qz,
                                            const __hip_bfloat16* interI, const __hip_bfloat16* hypI,
                                            float* ws, float* out) {
  __shared__ short LDS[18432];   // 36 KB
  int t = threadIdx.x;
  int R0 = blockIdx.x * 64;
  int w = t >> 6, lane = t & 63, quad = lane >> 4, l16 = lane & 15;
  const short* WTs = (const short*)(ws + OFF_WG2);
  const short* WQs = (const short*)(ws + OFF_WQT);
  const short* intS = (const short*)interI;
  const short* hypS = (const short*)hypI;

  // acc init: b_out[col] + biasg1_tail[row%11][col]
  fx4 acc[4][2];
  #pragma unroll
  for (int mt = 0; mt < 4; ++mt)
    #pragma unroll
    for (int reg = 0; reg < 4; ++reg) {
      int nidx = (R0 + mt*16 + quad*4 + reg) % 11;
      #pragma unroll
      for (int nt = 0; nt < 2; ++nt) {
        int col = w*32 + nt*16 + l16;
        acc[mt][nt][reg] = b_out[col] + ws[OFF_BIASG1 + nidx*1152 + 1024 + col];
      }
    }

  int ar = t >> 2, akq = (t & 3) * 16;   // A-stage: row, k-quarter
  int bn = t >> 1, bkh = (t & 1) * 32;   // B-stage: n-row, k-half
  for (int ch = 0; ch < 24; ++ch) {
    __syncthreads();
    { // stage A chunk (64 rows x 64 k) as bf16
      short tmp[16];
      if (ch < 15) {
        const float4* sp = (const float4*)(past + (size_t)(R0+ar)*960 + ch*64 + akq);
        #pragma unroll
        for (int q = 0; q < 4; ++q) {
          float4 v = sp[q];
          tmp[4*q+0]=f2bs(v.x); tmp[4*q+1]=f2bs(v.y); tmp[4*q+2]=f2bs(v.z); tmp[4*q+3]=f2bs(v.w);
        }
        *(bh8*)&LDS[A_OFF + ar*72 + akq]     = *(bh8*)&tmp[0];
        *(bh8*)&LDS[A_OFF + ar*72 + akq + 8] = *(bh8*)&tmp[8];
      } else if (ch < 23) {
        const short* s = ((ch < 19) ? intS : hypS) + (size_t)(R0+ar)*256 + ((ch < 19) ? (ch-15) : (ch-19))*64 + akq;
        *(bh8*)&LDS[A_OFF + ar*72 + akq]     = *(const bh8*)&s[0];
        *(bh8*)&LDS[A_OFF + ar*72 + akq + 8] = *(const bh8*)&s[8];
      } else {
        if (akq < 48) {
          const float4* sp = (const float4*)(inputs + (size_t)(R0+ar)*48 + akq);
          #pragma unroll
          for (int q = 0; q < 4; ++q) {
            float4 v = sp[q];
            tmp[4*q+0]=f2bs(v.x); tmp[4*q+1]=f2bs(v.y); tmp[4*q+2]=f2bs(v.z); tmp[4*q+3]=f2bs(v.w);
          }
        } else {
          #pragma unroll
          for (int q = 0; q < 16; ++q) tmp[q] = 0;
        }
        *(bh8*)&LDS[A_OFF + ar*72 + akq]     = *(bh8*)&tmp[0];
        *(bh8*)&LDS[A_OFF + ar*72 + akq + 8] = *(bh8*)&tmp[8];
      }
    }
    { // stage BT chunk (128 n x 64 k)
      const short* s = WTs + (size_t)bn*1536 + ch*64 + bkh;
      #pragma unroll
      for (int q = 0; q < 4; ++q)
        *(bh8*)&LDS[BT_OFF + bn*72 + bkh + q*8] = *(const bh8*)&s[q*8];
    }
    __syncthreads();
    #pragma unroll
    for (int ks = 0; ks < 2; ++ks) {
      int kk = ks*32 + quad*8;
      bh8 a[4], b[2];
      #pragma unroll
      for (int mt = 0; mt < 4; ++mt) a[mt] = *(const bh8*)&LDS[A_OFF + (mt*16 + l16)*72 + kk];
      #pragma unroll
      for (int nt = 0; nt < 2; ++nt) b[nt] = *(const bh8*)&LDS[BT_OFF + (w*32 + nt*16 + l16)*72 + kk];
      #pragma unroll
      for (int mt = 0; mt < 4; ++mt)
        #pragma unroll
        for (int nt = 0; nt < 2; ++nt)
          acc[mt][nt] = __builtin_amdgcn_mfma_f32_16x16x32_bf16(a[mt], b[nt], acc[mt][nt], 0, 0, 0);
    }
  }
  __syncthreads();
  // hs = relu(acc) as bf16 into LDS (C layout: row = quad*4+reg, col = l16 within tiles)
  #pragma unroll
  for (int mt = 0; mt < 4; ++mt)
    #pragma unroll
    for (int nt = 0; nt < 2; ++nt)
      #pragma unroll
      for (int reg = 0; reg < 4; ++reg)
        LDS[HS_OFF + (mt*16 + quad*4 + reg)*136 + w*32 + nt*16 + l16] = f2bs(fmaxf(acc[mt][nt][reg], 0.f));
  { // stage WQT (64 n x 128 k)
    int n = t >> 2, kh = (t & 3) * 32;
    const short* s = WQs + n*128 + kh;
    #pragma unroll
    for (int q = 0; q < 4; ++q)
      *(bh8*)&LDS[WQ_OFF + n*136 + kh + q*8] = *(const bh8*)&s[q*8];
  }
  __syncthreads();
  // out = h @ W_qz + b_qz : M=64, N=64 (16/wave), K=128
  fx4 acc2[4];
  {
    float bq = b_qz[w*16 + l16];
    #pragma unroll
    for (int mt = 0; mt < 4; ++mt) { acc2[mt][0]=bq; acc2[mt][1]=bq; acc2[mt][2]=bq; acc2[mt][3]=bq; }
  }
  #pragma unroll
  for (int ks = 0; ks < 4; ++ks) {
    int kk = ks*32 + quad*8;
    bh8 bb = *(const bh8*)&LDS[WQ_OFF + (w*16 + l16)*136 + kk];
    #pragma unroll
    for (int mt = 0; mt < 4; ++mt) {
      bh8 aa = *(const bh8*)&LDS[HS_OFF + (mt*16 + l16)*136 + kk];
      acc2[mt] = __builtin_amdgcn_mfma_f32_16x16x32_bf16(aa, bb, acc2[mt], 0, 0, 0);
    }
  }
  #pragma unroll
  for (int mt = 0; mt < 4; ++mt)
    #pragma unroll
    for (int reg = 0; reg < 4; ++reg)
      out[(size_t)(R0 + mt*16 + quad*4 + reg)*64 + w*16 + l16] = acc2[mt][reg];
}

extern "C" void kernel_launch(void* const* d_in, const int* in_sizes, int n_in,
                              void* d_out, int out_size, void* d_ws, size_t ws_size,
                              hipStream_t stream) {
  const float* inputs = (const float*)d_in[0];
  const float* past   = (const float*)d_in[1];
  const float* W_in   = (const float*)d_in[2];
  const float* b_in   = (const float*)d_in[3];
  const float* W_pos  = (const float*)d_in[4];
  const float* b_pos  = (const float*)d_in[5];
  const float* W_fc2  = (const float*)d_in[6];
  const float* b_fc2  = (const float*)d_in[7];
  const float* W_fc3  = (const float*)d_in[8];
  const float* b_fc3  = (const float*)d_in[9];
  const float* W_msg  = (const float*)d_in[10];
  const float* b_msg  = (const float*)d_in[11];
  const float* W_hyp  = (const float*)d_in[12];
  const float* b_hyp  = (const float*)d_in[13];
  const float* W_line = (const float*)d_in[14];
  const float* W_out  = (const float*)d_in[15];
  const float* b_out  = (const float*)d_in[16];
  const float* W_qz   = (const float*)d_in[17];
  const float* b_qz   = (const float*)d_in[18];
  float* ws = (float*)d_ws;
  __hip_bfloat16* interI = (__hip_bfloat16*)(ws + OFF_INTER);
  __hip_bfloat16* hypI   = interI + (size_t)BN*256;
  float* outp   = (float*)d_out;

  hipLaunchKernelGGL(k_p1, dim3(13),  dim3(256), 0, stream, W_in, b_in, W_pos, b_pos, ws);
  hipLaunchKernelGGL(k_p2, dim3(49),  dim3(256), 0, stream, W_fc2, b_fc2, ws);
  hipLaunchKernelGGL(k_p3, dim3(59),  dim3(256), 0, stream, W_fc3, b_fc3, ws);
  hipLaunchKernelGGL(k_p4, dim3(59),  dim3(256), 0, stream, W_msg, b_msg, W_hyp, b_hyp, W_out, ws);
  hipLaunchKernelGGL(k_p5, dim3(1536), dim3(128), 0, stream, W_line, W_out, ws);
  hipLaunchKernelGGL(k_p6, dim3(32),  dim3(256), 0, stream, W_qz, ws);
  hipLaunchKernelGGL(k_front, dim3(1024), dim3(256), 0, stream, inputs, ws);
  hipLaunchKernelGGL(k_mix, dim3(2048, 2), dim3(256), 0, stream, inputs, ws, interI, hypI);
  hipLaunchKernelGGL(k_g2, dim3(704), dim3(256), 0, stream, past, inputs, b_out, b_qz,
                     interI, hypI, ws, outp);
}

// Round 4
// 515.767 us; speedup vs baseline: 2.8323x; 1.8686x over previous
//
#include <hip/hip_runtime.h>
#include <hip/hip_bf16.h>

// Problem constants
#define BB 4096
#define NNA 11
#define BN (BB*NNA)      // 45056

// ws float offsets (f32 scratch unless noted)
#define OFF_WEFF   0         // [4][256]
#define OFF_BIASL  1024      // [12][256]
#define OFF_WBIG   4096      // [48][256]
#define OFF_BIAS2  16384     // [256]
#define OFF_WALL   16640     // [48][256]
#define OFF_BIASN  28928     // [11][256]
#define OFF_WG1F   31744     // [48][1152]
#define OFF_BIASG1 87040     // [11][1152]
#define OFF_WG2    99712     // bf16 WT[128][1536] (transposed tail weight), 98304 floats
#define OFF_WQT    198656    // bf16 WQT[64][128], 4096 floats
#define OFF_P2T    202752    // [12][256] per-l bias2 partials
#define OFF_P3T    205824    // [256] bias2@Wfc3_top
#define OFF_MIX    296320    // [4096][242]  attn(121)|A(121)
#define OFF_INTER  1287552   // bf16 region start (float-offset): inter[BN][256], hyp[BN][256]

typedef short bh8 __attribute__((ext_vector_type(8)));   // 8 bf16 (4 VGPRs) MFMA A/B frag
typedef float fx4 __attribute__((ext_vector_type(4)));   // MFMA C/D frag

__device__ __forceinline__ float b2f(__hip_bfloat16 x) { return __bfloat162float(x); }
__device__ __forceinline__ short f2bs(float v) { __hip_bfloat16 h = __float2bfloat16(v); return *(short*)&h; }

// ---------- Prologue: weight folding (f32, K-split mini-GEMMs) ----------
// Pattern: block = 64 cols x 4 K-slices; A staged in LDS (broadcast), B coalesced,
// acc[rows] in regs, 4-way K reduction through LDS.

// grid 4: C[16][256] = A[16][512] @ W_pos[512][256]
// A rows 0..3 = [W_in[c] | 0]  -> W_eff ; rows 4..15 = [b_in | pe_l] -> biasL (+b_pos)
__global__ __launch_bounds__(256) void k_p1(const float* W_in, const float* b_in,
                                            const float* W_pos, const float* b_pos,
                                            float* ws) {
  __shared__ float A[16*512];
  __shared__ float red[4*16*64];
  int t = threadIdx.x, cb = blockIdx.x;
  int ks = t >> 6, c = t & 63, col = cb*64 + c;
  float coef = -logf(10000.f) / 256.f;
  for (int i = t; i < 16*512; i += 256) {
    int row = i >> 9, kk = i & 511;
    float v;
    if (row < 4) v = (kk < 256) ? W_in[row*256 + kk] : 0.f;
    else if (kk < 256) v = b_in[kk];
    else {
      int ii = (kk - 256) >> 1;
      float dv = expf(coef * (float)(2*ii));
      float ang = (float)(row - 4) * dv;
      v = (kk & 1) ? cosf(ang) : sinf(ang);
    }
    A[i] = v;
  }
  __syncthreads();
  float acc[16];
  #pragma unroll
  for (int r = 0; r < 16; ++r) acc[r] = 0.f;
  #pragma unroll 4
  for (int j = 0; j < 128; ++j) {
    int jj = ks*128 + j;
    float b = W_pos[(size_t)jj*256 + col];
    #pragma unroll
    for (int r = 0; r < 16; ++r) acc[r] += A[r*512 + jj] * b;
  }
  #pragma unroll
  for (int r = 0; r < 16; ++r) red[(ks*16 + r)*64 + c] = acc[r];
  __syncthreads();
  for (int i = t; i < 16*64; i += 256) {
    int row = i >> 6, cc = i & 63;
    float s = red[row*64+cc] + red[(16+row)*64+cc] + red[(32+row)*64+cc] + red[(48+row)*64+cc];
    int gcol = cb*64 + cc;
    if (row < 4) ws[OFF_WEFF + row*256 + gcol] = s;
    else         ws[OFF_BIASL + (row-4)*256 + gcol] = s + b_pos[gcol];
  }
}

// grid (4,12): per l, C[5][256] = A_l[5][256] @ W_fc2_l ; rows 0..3 -> W_big[l*4+c], row 4 -> P2T[l]
__global__ __launch_bounds__(256) void k_p2(const float* W_fc2, float* ws) {
  __shared__ float A[5*256];
  __shared__ float red[4*5*64];
  int t = threadIdx.x, cb = blockIdx.x, l = blockIdx.y;
  int ks = t >> 6, c = t & 63, col = cb*64 + c;
  for (int i = t; i < 5*256; i += 256) {
    int row = i >> 8, kk = i & 255;
    A[i] = (row < 4) ? ws[OFF_WEFF + row*256 + kk] : ws[OFF_BIASL + l*256 + kk];
  }
  __syncthreads();
  float acc[5] = {0.f, 0.f, 0.f, 0.f, 0.f};
  #pragma unroll 4
  for (int j = 0; j < 64; ++j) {
    int jj = ks*64 + j;
    float b = W_fc2[(size_t)(l*256 + jj)*256 + col];
    #pragma unroll
    for (int r = 0; r < 5; ++r) acc[r] += A[r*256 + jj] * b;
  }
  #pragma unroll
  for (int r = 0; r < 5; ++r) red[(ks*5 + r)*64 + c] = acc[r];
  __syncthreads();
  for (int i = t; i < 5*64; i += 256) {
    int row = i / 64, cc = i % 64;
    float s = red[row*64+cc] + red[(5+row)*64+cc] + red[(10+row)*64+cc] + red[(15+row)*64+cc];
    int gcol = cb*64 + cc;
    if (row < 4) ws[OFF_WBIG + (l*4 + row)*256 + gcol] = s;
    else         ws[OFF_P2T + l*256 + gcol] = s;
  }
}

// grid 1: bias2 = b_fc2 + sum_l P2T[l]
__global__ __launch_bounds__(256) void k_p2b(const float* b_fc2, float* ws) {
  int d = threadIdx.x;
  float s = b_fc2[d];
  #pragma unroll
  for (int l = 0; l < 12; ++l) s += ws[OFF_P2T + l*256 + d];
  ws[OFF_BIAS2 + d] = s;
}

// grid (4,7): C[49][256] = A[49][256] @ W_fc3_top ; rows 0..47 -> W_all, row 48 -> P3T
__global__ __launch_bounds__(256) void k_p3(const float* W_fc3, float* ws) {
  __shared__ float A[7*256];
  __shared__ float red[4*7*64];
  int t = threadIdx.x, cb = blockIdx.x, rg = blockIdx.y;
  int ks = t >> 6, c = t & 63, col = cb*64 + c;
  for (int i = t; i < 7*256; i += 256) {
    int row = i >> 8, kk = i & 255, gr = rg*7 + row;
    A[i] = (gr < 48) ? ws[OFF_WBIG + gr*256 + kk] : (gr == 48 ? ws[OFF_BIAS2 + kk] : 0.f);
  }
  __syncthreads();
  float acc[7] = {0.f,0.f,0.f,0.f,0.f,0.f,0.f};
  #pragma unroll 4
  for (int j = 0; j < 64; ++j) {
    int jj = ks*64 + j;
    float b = W_fc3[(size_t)jj*256 + col];
    #pragma unroll
    for (int r = 0; r < 7; ++r) acc[r] += A[r*256 + jj] * b;
  }
  #pragma unroll
  for (int r = 0; r < 7; ++r) red[(ks*7 + r)*64 + c] = acc[r];
  __syncthreads();
  for (int i = t; i < 7*64; i += 256) {
    int row = i / 64, cc = i % 64, gr = rg*7 + row;
    float s = red[row*64+cc] + red[(7+row)*64+cc] + red[(14+row)*64+cc] + red[(21+row)*64+cc];
    int gcol = cb*64 + cc;
    if (gr < 48)       ws[OFF_WALL + gr*256 + gcol] = s;
    else if (gr == 48) ws[OFF_P3T + gcol] = s;
  }
}

// grid 11: bias_n[n] = P3T + b_fc3 + W_fc3[256+n]
__global__ __launch_bounds__(256) void k_p3b(const float* W_fc3, const float* b_fc3, float* ws) {
  int d = threadIdx.x, n = blockIdx.x;
  ws[OFF_BIASN + n*256 + d] = ws[OFF_P3T + d] + b_fc3[d] + W_fc3[(size_t)(256+n)*256 + d];
}

// Wg1 column map: [Wm_top|Wm_bot|Wh_top|Wh_bot|Wo_ftraj] (1152 cols)
__device__ __forceinline__ float wg1_elem(int j, int col, const float* W_msg,
                                          const float* W_hyp, const float* W_out) {
  if (col < 256)       return W_msg[j*256 + col];
  else if (col < 512)  return W_msg[(256+j)*256 + (col-256)];
  else if (col < 768)  return W_hyp[j*256 + (col-512)];
  else if (col < 1024) return W_hyp[(256+j)*256 + (col-768)];
  else                 return W_out[(960+j)*128 + (col-1024)];
}

// grid (18,8): C[59][1152] = A[59][256] @ Wg1 ; rows 0..47 -> Wg1f, 48..58 -> biasg1 (+b_msg/b_hyp)
__global__ __launch_bounds__(256) void k_p4(const float* W_msg, const float* b_msg,
                                            const float* W_hyp, const float* b_hyp,
                                            const float* W_out, float* ws) {
  __shared__ float A[8*256];
  __shared__ float red[4*8*64];
  int t = threadIdx.x, cb = blockIdx.x, rg = blockIdx.y;
  int ks = t >> 6, c = t & 63, col = cb*64 + c;
  for (int i = t; i < 8*256; i += 256) {
    int row = i >> 8, kk = i & 255, gr = rg*8 + row;
    A[i] = (gr < 48) ? ws[OFF_WALL + gr*256 + kk]
         : (gr < 59 ? ws[OFF_BIASN + (gr-48)*256 + kk] : 0.f);
  }
  __syncthreads();
  float acc[8];
  #pragma unroll
  for (int r = 0; r < 8; ++r) acc[r] = 0.f;
  #pragma unroll 4
  for (int j = 0; j < 64; ++j) {
    int jj = ks*64 + j;
    float b = wg1_elem(jj, col, W_msg, W_hyp, W_out);
    #pragma unroll
    for (int r = 0; r < 8; ++r) acc[r] += A[r*256 + jj] * b;
  }
  #pragma unroll
  for (int r = 0; r < 8; ++r) red[(ks*8 + r)*64 + c] = acc[r];
  __syncthreads();
  for (int i = t; i < 8*64; i += 256) {
    int row = i >> 6, cc = i & 63, gr = rg*8 + row;
    float s = red[row*64+cc] + red[(8+row)*64+cc] + red[(16+row)*64+cc] + red[(24+row)*64+cc];
    int gcol = cb*64 + cc;
    if (gr < 48) {
      ws[OFF_WG1F + gr*1152 + gcol] = s;
    } else if (gr < 59) {
      if (gcol < 256) s += b_msg[gcol];
      else if (gcol >= 512 && gcol < 768) s += b_hyp[gcol-512];
      ws[OFF_BIASG1 + (gr-48)*1152 + gcol] = s;
    }
  }
}

// grid 1536, block 128: WT[c][r] (bf16, transposed) for the tail MFMA GEMM:
// rows 0..959: W_out past; 960..1215: W_out inter-rows; 1216..1471: W_line@W_out_feat; 1472..1519: Wg1f[:,1024:]; rest 0
__global__ __launch_bounds__(128) void k_p5(const float* W_line, const float* W_out,
                                            float* ws) {
  int c = threadIdx.x, r = blockIdx.x;
  float v;
  if (r < 960)       v = W_out[r*128 + c];
  else if (r < 1216) v = W_out[(r+256)*128 + c];
  else if (r < 1472) {
    int dd = r - 1216;
    float s = 0.f;
    for (int j = 0; j < 64; ++j)
      s += W_line[dd*64 + j] * W_out[(1472+j)*128 + c];
    v = s;
  } else if (r < 1520) {
    v = ws[OFF_WG1F + (r-1472)*1152 + 1024 + c];
  } else v = 0.f;
  short* WTs = (short*)(ws + OFF_WG2);
  WTs[(size_t)c*1536 + r] = f2bs(v);
}

// grid 32, block 256: WQT[n][k] = bf16(W_qz[k][n]) for the qz epilogue MFMA
__global__ __launch_bounds__(256) void k_p6(const float* W_qz, float* ws) {
  int i = blockIdx.x*256 + threadIdx.x;
  int n = i >> 7, k = i & 127;
  short* WQs = (short*)(ws + OFF_WQT);
  WQs[n*128 + k] = f2bs(W_qz[k*64 + n]);
}

// ---------- Front: ftraj GEMM (K=48) + per-scene corr -> attn/A ----------
// grid 1024: 4 scenes (44 rows) per block; one wave per scene for corr/attn/A.
__global__ __launch_bounds__(256) void k_front(const float* inputs, float* ws) {
  __shared__ float XT[48*44];     // transposed x: XT[k*44 + r]
  __shared__ float F[44*260];     // ftraj tile, padded stride 260 (16B aligned rows)
  __shared__ float C[4*121];      // per-scene gram
  int t = threadIdx.x;
  int R0 = blockIdx.x * 44;
  for (int i = t; i < 44*48; i += 256) {
    int r = i / 48, k = i - r*48;
    XT[k*44 + r] = inputs[(size_t)(R0+r)*48 + k];
  }
  __syncthreads();
  { // ftraj = X48 @ W_all + bias_n ; thread = output col d
    int d = t;
    float acc[44];
    #pragma unroll
    for (int r = 0; r < 44; ++r) acc[r] = ws[OFF_BIASN + (r % 11)*256 + d];
    for (int k = 0; k < 48; ++k) {
      float w = ws[OFF_WALL + k*256 + d];
      #pragma unroll
      for (int j = 0; j < 11; ++j) {
        float4 xv = *(const float4*)&XT[k*44 + 4*j];
        acc[4*j+0] += xv.x*w; acc[4*j+1] += xv.y*w;
        acc[4*j+2] += xv.z*w; acc[4*j+3] += xv.w*w;
      }
    }
    #pragma unroll
    for (int r = 0; r < 44; ++r) F[r*260 + d] = acc[r];
  }
  __syncthreads();
  int w = t >> 6, lane = t & 63;
  { // gram: 66 unique pairs per scene, one wave per scene
    const float4* F4 = (const float4*)F;   // row stride 65 float4s
    for (int p = lane; p < 66; p += 64) {
      int n = 0, pp = p;
      while (pp >= 11 - n) { pp -= 11 - n; ++n; }
      int m = n + pp;
      int ra = (w*11 + n) * 65, rb2 = (w*11 + m) * 65;
      float s = 0.f;
      #pragma unroll 4
      for (int j = 0; j < 64; ++j) {
        float4 a = F4[ra + j], b = F4[rb2 + j];
        s += a.x*b.x + a.y*b.y + a.z*b.z + a.w*b.w;
      }
      C[w*121 + n*11 + m] = s;
      C[w*121 + m*11 + n] = s;
    }
  }
  __syncthreads();
  { // attn (softmax of C/16) and A (thresholded, degree-normalized)
    float* Cw = C + w*121;
    float rn[11];
    #pragma unroll
    for (int n = 0; n < 11; ++n) rn[n] = 1.f / sqrtf(Cw[n*11+n]);
    float a = 1e30f;
    for (int n = 0; n < 11; ++n)
      for (int m = 0; m < 11; ++m)
        a = fminf(a, Cw[n*11+m] * rn[n] * rn[m]);
    float thr = (a < 0.4f) ? 0.4f : (((a > 0.4f) && (a < 0.6f)) ? a + 0.1f : a + 0.03f);
    int scene = blockIdx.x*4 + w;
    float* mixb = ws + OFF_MIX + (size_t)scene*242;
    if (lane < 11) {
      int n = lane;
      float mx = -1e30f;
      #pragma unroll
      for (int m = 0; m < 11; ++m) mx = fmaxf(mx, Cw[n*11+m]);
      mx *= (1.f/16.f);
      float e[11], ssum = 0.f;
      #pragma unroll
      for (int m = 0; m < 11; ++m) { e[m] = expf(Cw[n*11+m]*(1.f/16.f) - mx); ssum += e[m]; }
      float inv = 1.f / ssum;
      #pragma unroll
      for (int m = 0; m < 11; ++m) mixb[n*11+m] = e[m]*inv;
      float keep[11], cnt = 0.f;
      #pragma unroll
      for (int m = 0; m < 11; ++m) {
        float q = Cw[n*11+m] * rn[n] * rn[m];
        keep[m] = (q >= thr) ? 1.f : 0.f; cnt += keep[m];
      }
      float sc = 1.f / fmaxf(cnt, 1.f);
      #pragma unroll
      for (int m = 0; m < 11; ++m) mixb[121 + n*11 + m] = keep[m]*sc;
    }
  }
}

// ---------- Mix: P = X48 @ Wg1f (+bias), register attn/A mixing, relu -> inter/hyp (bf16) ----------
// grid (2048, 2): 2 scenes (22 rows) per block; gy=0 -> msg/inter (attn), gy=1 -> hyp (A).
__global__ __launch_bounds__(256) void k_mix(const float* inputs, float* ws,
                                             __hip_bfloat16* outI, __hip_bfloat16* outH) {
  __shared__ float XT[48*24];   // XT[k*24+r], rows 22,23 zero
  __shared__ float MW[2*121];
  int t = threadIdx.x;
  int s0 = blockIdx.x * 2;
  int R0 = s0 * 11;
  int gy = blockIdx.y;
  __hip_bfloat16* dst = gy ? outH : outI;
  for (int i = t; i < 22*48; i += 256) {
    int r = i / 48, k = i - r*48;
    XT[k*24 + r] = inputs[(size_t)(R0+r)*48 + k];
  }
  for (int i = t; i < 96; i += 256) { int k = i >> 1, r = 22 + (i & 1); XT[k*24+r] = 0.f; }
  for (int i = t; i < 242; i += 256) {
    int s = i / 121, j = i - s*121;
    MW[i] = ws[OFF_MIX + (size_t)(s0+s)*242 + gy*121 + j];
  }
  __syncthreads();
  int gc = gy*512 + t;           // top col; bot col = gc+256
  float accT[24], accB[24];
  #pragma unroll
  for (int r = 0; r < 24; ++r) {
    if (r < 22) {
      accT[r] = ws[OFF_BIASG1 + (r % 11)*1152 + gc];
      accB[r] = ws[OFF_BIASG1 + (r % 11)*1152 + gc + 256];
    } else { accT[r] = 0.f; accB[r] = 0.f; }
  }
  for (int k = 0; k < 48; ++k) {
    float wt = ws[OFF_WG1F + k*1152 + gc];
    float wb = ws[OFF_WG1F + k*1152 + gc + 256];
    #pragma unroll
    for (int j = 0; j < 6; ++j) {
      float4 xv = *(const float4*)&XT[k*24 + 4*j];
      accT[4*j+0] += xv.x*wt; accT[4*j+1] += xv.y*wt; accT[4*j+2] += xv.z*wt; accT[4*j+3] += xv.w*wt;
      accB[4*j+0] += xv.x*wb; accB[4*j+1] += xv.y*wb; accB[4*j+2] += xv.z*wb; accB[4*j+3] += xv.w*wb;
    }
  }
  #pragma unroll
  for (int s = 0; s < 2; ++s)
    #pragma unroll
    for (int n = 0; n < 11; ++n) {
      float v = accT[s*11+n];
      #pragma unroll
      for (int m = 0; m < 11; ++m)
        v += MW[s*121 + n*11 + m] * accB[s*11+m];
      v = fmaxf(v, 0.f);
      dst[(size_t)(R0 + s*11 + n)*256 + t] = __float2bfloat16(v);
    }
}

// ---------- Tail: bf16 MFMA GEMM. h = relu([past|inter|hyp|X48] @ WT^T + biases); out = h @ WQT^T + b_qz ----------
// grid 704, block 256 (4 waves). Tile M=64 x N=128, K=1536 in 24 chunks of 64.
// LDS (shorts): A[64][72] @0 (4608) | BT[128][72] @4608 (9216) ; epilogue: hs[64][136] @0 | WQ[64][136] @8704.
#define A_OFF 0
#define BT_OFF 4608
#define HS_OFF 0
#define WQ_OFF 8704
__global__ __launch_bounds__(256) void k_g2(const float* past, const float* inputs,
                                            const float* b_out, const float* b_qz,
                                            const __hip_bfloat16* interI, const __hip_bfloat16* hypI,
                                            float* ws, float* out) {
  __shared__ short LDS[18432];   // 36 KB
  int t = threadIdx.x;
  int R0 = blockIdx.x * 64;
  int w = t >> 6, lane = t & 63, quad = lane >> 4, l16 = lane & 15;
  const short* WTs = (const short*)(ws + OFF_WG2);
  const short* WQs = (const short*)(ws + OFF_WQT);
  const short* intS = (const short*)interI;
  const short* hypS = (const short*)hypI;

  // acc init: b_out[col] + biasg1_tail[row%11][col]
  fx4 acc[4][2];
  #pragma unroll
  for (int mt = 0; mt < 4; ++mt)
    #pragma unroll
    for (int reg = 0; reg < 4; ++reg) {
      int nidx = (R0 + mt*16 + quad*4 + reg) % 11;
      #pragma unroll
      for (int nt = 0; nt < 2; ++nt) {
        int col = w*32 + nt*16 + l16;
        acc[mt][nt][reg] = b_out[col] + ws[OFF_BIASG1 + nidx*1152 + 1024 + col];
      }
    }

  int ar = t >> 2, akq = (t & 3) * 16;   // A-stage: row, k-quarter
  int bn = t >> 1, bkh = (t & 1) * 32;   // B-stage: n-row, k-half
  for (int ch = 0; ch < 24; ++ch) {
    __syncthreads();
    { // stage A chunk (64 rows x 64 k) as bf16
      short tmp[16];
      if (ch < 15) {
        const float4* sp = (const float4*)(past + (size_t)(R0+ar)*960 + ch*64 + akq);
        #pragma unroll
        for (int q = 0; q < 4; ++q) {
          float4 v = sp[q];
          tmp[4*q+0]=f2bs(v.x); tmp[4*q+1]=f2bs(v.y); tmp[4*q+2]=f2bs(v.z); tmp[4*q+3]=f2bs(v.w);
        }
        *(bh8*)&LDS[A_OFF + ar*72 + akq]     = *(bh8*)&tmp[0];
        *(bh8*)&LDS[A_OFF + ar*72 + akq + 8] = *(bh8*)&tmp[8];
      } else if (ch < 23) {
        const short* s = ((ch < 19) ? intS : hypS) + (size_t)(R0+ar)*256 + ((ch < 19) ? (ch-15) : (ch-19))*64 + akq;
        *(bh8*)&LDS[A_OFF + ar*72 + akq]     = *(const bh8*)&s[0];
        *(bh8*)&LDS[A_OFF + ar*72 + akq + 8] = *(const bh8*)&s[8];
      } else {
        if (akq < 48) {
          const float4* sp = (const float4*)(inputs + (size_t)(R0+ar)*48 + akq);
          #pragma unroll
          for (int q = 0; q < 4; ++q) {
            float4 v = sp[q];
            tmp[4*q+0]=f2bs(v.x); tmp[4*q+1]=f2bs(v.y); tmp[4*q+2]=f2bs(v.z); tmp[4*q+3]=f2bs(v.w);
          }
        } else {
          #pragma unroll
          for (int q = 0; q < 16; ++q) tmp[q] = 0;
        }
        *(bh8*)&LDS[A_OFF + ar*72 + akq]     = *(bh8*)&tmp[0];
        *(bh8*)&LDS[A_OFF + ar*72 + akq + 8] = *(bh8*)&tmp[8];
      }
    }
    { // stage BT chunk (128 n x 64 k)
      const short* s = WTs + (size_t)bn*1536 + ch*64 + bkh;
      #pragma unroll
      for (int q = 0; q < 4; ++q)
        *(bh8*)&LDS[BT_OFF + bn*72 + bkh + q*8] = *(const bh8*)&s[q*8];
    }
    __syncthreads();
    #pragma unroll
    for (int ks = 0; ks < 2; ++ks) {
      int kk = ks*32 + quad*8;
      bh8 a[4], b[2];
      #pragma unroll
      for (int mt = 0; mt < 4; ++mt) a[mt] = *(const bh8*)&LDS[A_OFF + (mt*16 + l16)*72 + kk];
      #pragma unroll
      for (int nt = 0; nt < 2; ++nt) b[nt] = *(const bh8*)&LDS[BT_OFF + (w*32 + nt*16 + l16)*72 + kk];
      #pragma unroll
      for (int mt = 0; mt < 4; ++mt)
        #pragma unroll
        for (int nt = 0; nt < 2; ++nt)
          acc[mt][nt] = __builtin_amdgcn_mfma_f32_16x16x32_bf16(a[mt], b[nt], acc[mt][nt], 0, 0, 0);
    }
  }
  __syncthreads();
  // hs = relu(acc) as bf16 into LDS (C layout: row = quad*4+reg, col = l16 within tiles)
  #pragma unroll
  for (int mt = 0; mt < 4; ++mt)
    #pragma unroll
    for (int nt = 0; nt < 2; ++nt)
      #pragma unroll
      for (int reg = 0; reg < 4; ++reg)
        LDS[HS_OFF + (mt*16 + quad*4 + reg)*136 + w*32 + nt*16 + l16] = f2bs(fmaxf(acc[mt][nt][reg], 0.f));
  { // stage WQT (64 n x 128 k)
    int n = t >> 2, kh = (t & 3) * 32;
    const short* s = WQs + n*128 + kh;
    #pragma unroll
    for (int q = 0; q < 4; ++q)
      *(bh8*)&LDS[WQ_OFF + n*136 + kh + q*8] = *(const bh8*)&s[q*8];
  }
  __syncthreads();
  // out = h @ W_qz + b_qz : M=64, N=64 (16/wave), K=128
  fx4 acc2[4];
  {
    float bq = b_qz[w*16 + l16];
    #pragma unroll
    for (int mt = 0; mt < 4; ++mt) { acc2[mt][0]=bq; acc2[mt][1]=bq; acc2[mt][2]=bq; acc2[mt][3]=bq; }
  }
  #pragma unroll
  for (int ks = 0; ks < 4; ++ks) {
    int kk = ks*32 + quad*8;
    bh8 bb = *(const bh8*)&LDS[WQ_OFF + (w*16 + l16)*136 + kk];
    #pragma unroll
    for (int mt = 0; mt < 4; ++mt) {
      bh8 aa = *(const bh8*)&LDS[HS_OFF + (mt*16 + l16)*136 + kk];
      acc2[mt] = __builtin_amdgcn_mfma_f32_16x16x32_bf16(aa, bb, acc2[mt], 0, 0, 0);
    }
  }
  #pragma unroll
  for (int mt = 0; mt < 4; ++mt)
    #pragma unroll
    for (int reg = 0; reg < 4; ++reg)
      out[(size_t)(R0 + mt*16 + quad*4 + reg)*64 + w*16 + l16] = acc2[mt][reg];
}

extern "C" void kernel_launch(void* const* d_in, const int* in_sizes, int n_in,
                              void* d_out, int out_size, void* d_ws, size_t ws_size,
                              hipStream_t stream) {
  const float* inputs = (const float*)d_in[0];
  const float* past   = (const float*)d_in[1];
  const float* W_in   = (const float*)d_in[2];
  const float* b_in   = (const float*)d_in[3];
  const float* W_pos  = (const float*)d_in[4];
  const float* b_pos  = (const float*)d_in[5];
  const float* W_fc2  = (const float*)d_in[6];
  const float* b_fc2  = (const float*)d_in[7];
  const float* W_fc3  = (const float*)d_in[8];
  const float* b_fc3  = (const float*)d_in[9];
  const float* W_msg  = (const float*)d_in[10];
  const float* b_msg  = (const float*)d_in[11];
  const float* W_hyp  = (const float*)d_in[12];
  const float* b_hyp  = (const float*)d_in[13];
  const float* W_line = (const float*)d_in[14];
  const float* W_out  = (const float*)d_in[15];
  const float* b_out  = (const float*)d_in[16];
  const float* W_qz   = (const float*)d_in[17];
  const float* b_qz   = (const float*)d_in[18];
  float* ws = (float*)d_ws;
  __hip_bfloat16* interI = (__hip_bfloat16*)(ws + OFF_INTER);
  __hip_bfloat16* hypI   = interI + (size_t)BN*256;
  float* outp   = (float*)d_out;

  hipLaunchKernelGGL(k_p1,  dim3(4),      dim3(256), 0, stream, W_in, b_in, W_pos, b_pos, ws);
  hipLaunchKernelGGL(k_p2,  dim3(4, 12),  dim3(256), 0, stream, W_fc2, ws);
  hipLaunchKernelGGL(k_p2b, dim3(1),      dim3(256), 0, stream, b_fc2, ws);
  hipLaunchKernelGGL(k_p3,  dim3(4, 7),   dim3(256), 0, stream, W_fc3, ws);
  hipLaunchKernelGGL(k_p3b, dim3(11),     dim3(256), 0, stream, W_fc3, b_fc3, ws);
  hipLaunchKernelGGL(k_p4,  dim3(18, 8),  dim3(256), 0, stream, W_msg, b_msg, W_hyp, b_hyp, W_out, ws);
  hipLaunchKernelGGL(k_p5,  dim3(1536),   dim3(128), 0, stream, W_line, W_out, ws);
  hipLaunchKernelGGL(k_p6,  dim3(32),     dim3(256), 0, stream, W_qz, ws);
  hipLaunchKernelGGL(k_front, dim3(1024), dim3(256), 0, stream, inputs, ws);
  hipLaunchKernelGGL(k_mix, dim3(2048, 2), dim3(256), 0, stream, inputs, ws, interI, hypI);
  hipLaunchKernelGGL(k_g2,  dim3(704),    dim3(256), 0, stream, past, inputs, b_out, b_qz,
                     interI, hypI, ws, outp);
}